// Round 7
// baseline (85.231 us; speedup 1.0000x reference)
//
#include <hip/hip_runtime.h>
#include <hip/hip_bf16.h>
#include <math.h>

// Problem dims
#define BB 2
#define LL 2048
#define DD 768
#define D3 2304
#define HH 12
#define EE 32
#define RR 57
#define NN 20
#define PP 248
#define MM 256          // P padded to 256
#define KS 8            // K-split in score GEMM
#define R80 80          // R+N=77 padded to 80 (5x16)

// ws layout (float offsets)
#define ENT_EMB_OFF 0                           // f32 B*E*D = 49152
#define A16_OFF   (BB * EE * DD)                // bf16 [B][MM][LL] (unnormalized q)
#define A16_F     (BB * MM * LL / 2)
#define SCT_OFF   (A16_OFF + A16_F)             // bf16 [B][R80][LL] = seq @ code_c^T
#define SCT_F     (BB * R80 * LL / 2)
#define ES_OFF    (SCT_OFF + SCT_F)             // f32 [B][2][EE][R80] (slot 0=s,1=o)
#define ES_F      (BB * 2 * EE * R80)
#define SPART_OFF (ES_OFF + ES_F)               // f32 [B][KS][MM][R80]
#define SPART_F   (BB * KS * MM * R80)
#define QPART_OFF (SPART_OFF + SPART_F)         // f32 [B][KS][MM]

// K1 grid roles
#define NQBLK 256      // q pair rows (16-l chunks)
#define NEBLK 64       // ent_emb
#define NSBLK 64       // SCT GEMM (32 l-tiles x 2 b)

typedef __attribute__((ext_vector_type(8))) short bf16x8;
typedef __attribute__((ext_vector_type(4))) float f32x4;

__device__ __forceinline__ unsigned short f2bf(float f) {
    __hip_bfloat16 h = __float2bfloat16(f);
    return __builtin_bit_cast(unsigned short, h);
}
__device__ __forceinline__ float bf2f(unsigned short u) {
    unsigned int x = ((unsigned int)u) << 16;
    return __builtin_bit_cast(float, x);
}
__device__ __forceinline__ void pair_so(int p, int& s, int& o) {
    s = p / 31;
    int r = p - s * 31;
    o = (r < s) ? r : r + 1;
}
__device__ __forceinline__ void cast8(float4 u0, float4 u1, short* dst) {
    ushort4 a = make_ushort4(f2bf(u0.x), f2bf(u0.y), f2bf(u0.z), f2bf(u0.w));
    ushort4 b = make_ushort4(f2bf(u1.x), f2bf(u1.y), f2bf(u1.z), f2bf(u1.w));
    *(ushort4*)dst = a;
    *(ushort4*)(dst + 4) = b;
}
// code row r (0..79): rel[r] for r<57, nota[r-57] for r<77, else zero
__device__ __forceinline__ void stage_code8(const float* __restrict__ rel,
                                            const float* __restrict__ nota,
                                            int row, int slot, int off, short* dst) {
    if (row < RR) {
        const float* cp = rel + (size_t)row * D3 + slot * DD + off;
        cast8(*(const float4*)cp, *(const float4*)(cp + 4), dst);
    } else if (row < RR + NN) {
        const float* cp = nota + (size_t)(row - RR) * D3 + slot * DD + off;
        cast8(*(const float4*)cp, *(const float4*)(cp + 4), dst);
    } else {
        ushort4 z = make_ushort4(0, 0, 0, 0);
        *(ushort4*)dst = z;
        *(ushort4*)(dst + 4) = z;
    }
}

// ===== K1: role Q (att gather -> q rows), role E (ent_emb), role S (SCT GEMM) =====
__global__ __launch_bounds__(256) void k1_prep(const float* __restrict__ seq,
                                               const float* __restrict__ att,
                                               const float* __restrict__ rel,
                                               const float* __restrict__ nota,
                                               const int* __restrict__ spans,
                                               float* __restrict__ ws) {
    __shared__ __align__(16) char smem[24768];
    int bid = blockIdx.x;
    int t = threadIdx.x;

    if (bid < NQBLK) {
        // ---- role Q: gather+w-average attention into LDS, 256 pair rows ----
        float (*att_s)[EE * HH + 1] = (float (*)[EE * HH + 1])smem;
        int* sp_s = (int*)(smem + 16 * (EE * HH + 1) * 4);
        int b = bid >> 7, l0 = (bid & 127) * 16;
        if (t < EE) sp_s[t] = spans[b * EE + t];
        __syncthreads();
        for (int i = t; i < EE * HH * 4; i += 256) {
            int seg = i & 3, eh = i >> 2;
            int e = eh / HH, h = eh - e * HH;
            const float* base = att + ((size_t)(b * HH + h) * LL + sp_s[e]) * LL + l0 + seg * 4;
            float4 v0 = *(const float4*)base;
            float4 v1 = *(const float4*)(base + LL);
            float4 v2 = *(const float4*)(base + 2 * LL);
            float4 v3 = *(const float4*)(base + 3 * LL);
            att_s[seg * 4 + 0][eh] = 0.25f * (v0.x + v1.x + v2.x + v3.x);
            att_s[seg * 4 + 1][eh] = 0.25f * (v0.y + v1.y + v2.y + v3.y);
            att_s[seg * 4 + 2][eh] = 0.25f * (v0.z + v1.z + v2.z + v3.z);
            att_s[seg * 4 + 3][eh] = 0.25f * (v0.w + v1.w + v2.w + v3.w);
        }
        __syncthreads();
        int p = t, s, o;
        pair_so(p, s, o);          // pads p>=248 -> s=8 (valid entity)
        float q[16];
        #pragma unroll
        for (int l = 0; l < 16; ++l) {
            float acc = 0.f;
            #pragma unroll
            for (int h = 0; h < HH; ++h) acc += att_s[l][s * HH + h] * att_s[l][o * HH + h];
            q[l] = acc;
        }
        unsigned short* A16 = (unsigned short*)(ws + A16_OFF) + (size_t)(b * MM + p) * LL + l0;
        #pragma unroll
        for (int i = 0; i < 4; ++i) {
            ushort4 ov = make_ushort4(f2bf(q[i * 4 + 0]), f2bf(q[i * 4 + 1]),
                                      f2bf(q[i * 4 + 2]), f2bf(q[i * 4 + 3]));
            *(ushort4*)(A16 + i * 4) = ov;
        }
    } else if (bid < NQBLK + NEBLK) {
        // ---- role E: ent_emb ----
        int bx = bid - NQBLK;
        int e = bx & 31, b = bx >> 5;
        int st = spans[b * EE + e];
        float* ee = ws + ENT_EMB_OFF + (size_t)(b * EE + e) * DD;
        const float* srow = seq + (size_t)(b * LL + st) * DD;
        for (int d = t; d < DD; d += 256) {
            ee[d] = 0.25f * (srow[d] + srow[DD + d] + srow[2 * DD + d] + srow[3 * DD + d]);
        }
    } else {
        // ---- role S: SCT[b][r][l] = sum_d seq[b][l][d]*code[r][2D+d]  (bf16 MFMA) ----
        short (*As)[40] = (short (*)[40])smem;            // 64 l-rows
        short (*Bs)[40] = (short (*)[40])(smem + 5120);   // 80 r-rows
        int x = bid - NQBLK - NEBLK;
        int b = x >> 5, l0 = (x & 31) * 64;
        int w = t >> 6, lane = t & 63, fr = lane & 15, kb = lane >> 4;
        int arow = t >> 2, aseg = t & 3;
        f32x4 acc[5] = {};
        for (int d0 = 0; d0 < DD; d0 += 32) {
            const float* sp = seq + (size_t)(b * LL + l0 + arow) * DD + d0 + aseg * 8;
            cast8(*(const float4*)sp, *(const float4*)(sp + 4), &As[arow][aseg * 8]);
            for (int i = t; i < R80 * 4; i += 256) {
                int row = i >> 2, seg = i & 3;
                stage_code8(rel, nota, row, 2, d0 + seg * 8, &Bs[row][seg * 8]);
            }
            __syncthreads();
            bf16x8 af = *(bf16x8*)&As[w * 16 + fr][kb * 8];
            #pragma unroll
            for (int j = 0; j < 5; ++j) {
                bf16x8 bf = *(bf16x8*)&Bs[j * 16 + fr][kb * 8];
                acc[j] = __builtin_amdgcn_mfma_f32_16x16x32_bf16(af, bf, acc[j], 0, 0, 0);
            }
            __syncthreads();
        }
        unsigned short* sct = (unsigned short*)(ws + SCT_OFF);
        #pragma unroll
        for (int j = 0; j < 5; ++j) {
            int r = j * 16 + fr;
            int lloc = l0 + w * 16 + kb * 4;
            ushort4 ov = make_ushort4(f2bf(acc[j][0]), f2bf(acc[j][1]),
                                      f2bf(acc[j][2]), f2bf(acc[j][3]));
            *(ushort4*)(sct + (size_t)(b * R80 + r) * LL + lloc) = ov;
        }
    }
}

// ===== K2: role QS (score GEMM + qpart), role EO (ES/EO GEMM) =====
__global__ __launch_bounds__(256) void k2_gemm(const float* __restrict__ rel,
                                               const float* __restrict__ nota,
                                               float* __restrict__ ws) {
    __shared__ __align__(16) char smem[12544];
    short (*As)[40] = (short (*)[40])smem;            // 64 rows
    short (*Bs)[40] = (short (*)[40])(smem + 5120);   // 80 rows
    float (*qred)[4] = (float (*)[4])(smem + 11520);  // [64][4]
    int bid = blockIdx.x;
    int t = threadIdx.x;
    int w = t >> 6, lane = t & 63, fr = lane & 15, kb = lane >> 4;
    int arow = t >> 2, aseg = t & 3;

    if (bid < 64) {
        // ---- role QS: spart[b][ks][m][r] = sum_{l in chunk} q[m][l]*SCT[r][l] ----
        int m0 = (bid & 3) * 64, ks = (bid >> 2) & 7, b = bid >> 5;
        int k0 = ks * 256;
        const unsigned short* A16 =
            (const unsigned short*)(ws + A16_OFF) + (size_t)b * MM * LL;
        const unsigned short* SCT =
            (const unsigned short*)(ws + SCT_OFF) + (size_t)b * R80 * LL;
        float qacc = 0.f;
        f32x4 acc[5] = {};
        for (int st = 0; st < 8; ++st) {
            int kk = k0 + st * 32;
            uint4 av = *(const uint4*)(A16 + (size_t)(m0 + arow) * LL + kk + aseg * 8);
            *(uint4*)&As[arow][aseg * 8] = av;
            const unsigned short* au = (const unsigned short*)&av;
            #pragma unroll
            for (int i = 0; i < 8; ++i) qacc += bf2f(au[i]);
            for (int i = t; i < R80 * 4; i += 256) {
                int row = i >> 2, seg = i & 3;
                *(uint4*)&Bs[row][seg * 8] =
                    *(const uint4*)(SCT + (size_t)row * LL + kk + seg * 8);
            }
            __syncthreads();
            bf16x8 af = *(bf16x8*)&As[w * 16 + fr][kb * 8];
            #pragma unroll
            for (int j = 0; j < 5; ++j) {
                bf16x8 bf = *(bf16x8*)&Bs[j * 16 + fr][kb * 8];
                acc[j] = __builtin_amdgcn_mfma_f32_16x16x32_bf16(af, bf, acc[j], 0, 0, 0);
            }
            __syncthreads();
        }
        qred[arow][aseg] = qacc;
        __syncthreads();
        if (t < 64) {
            ws[QPART_OFF + (size_t)(b * KS + ks) * MM + m0 + t] =
                qred[t][0] + qred[t][1] + qred[t][2] + qred[t][3];
        }
        float* sp = ws + SPART_OFF + ((size_t)(b * KS + ks) * MM + m0) * R80;
        #pragma unroll
        for (int j = 0; j < 5; ++j)
            #pragma unroll
            for (int r = 0; r < 4; ++r)
                sp[(size_t)(w * 16 + kb * 4 + r) * R80 + j * 16 + fr] = acc[j][r];
    } else {
        // ---- role EO: ES_tab[b][slot][e][r] = ent_emb[e] . code[r][slot*D..] ----
        int x = bid - 64;
        int slot = x & 1, b = x >> 1;
        f32x4 acc[5] = {};
        for (int d0 = 0; d0 < DD; d0 += 32) {
            if (t < 128) {
                const float* ep =
                    ws + ENT_EMB_OFF + (size_t)(b * EE + arow) * DD + d0 + aseg * 8;
                cast8(*(const float4*)ep, *(const float4*)(ep + 4), &As[arow][aseg * 8]);
            }
            for (int i = t; i < R80 * 4; i += 256) {
                int row = i >> 2, seg = i & 3;
                stage_code8(rel, nota, row, slot, d0 + seg * 8, &Bs[row][seg * 8]);
            }
            __syncthreads();
            if (w < 2) {
                bf16x8 af = *(bf16x8*)&As[w * 16 + fr][kb * 8];
                #pragma unroll
                for (int j = 0; j < 5; ++j) {
                    bf16x8 bf = *(bf16x8*)&Bs[j * 16 + fr][kb * 8];
                    acc[j] = __builtin_amdgcn_mfma_f32_16x16x32_bf16(af, bf, acc[j], 0, 0, 0);
                }
            }
            __syncthreads();
        }
        if (w < 2) {
            float* es = ws + ES_OFF + (size_t)((b * 2 + slot) * EE) * R80;
            #pragma unroll
            for (int j = 0; j < 5; ++j)
                #pragma unroll
                for (int r = 0; r < 4; ++r)
                    es[(size_t)(w * 16 + kb * 4 + r) * R80 + j * 16 + fr] = acc[j][r];
        }
    }
}

// ===== K3: compose scores + nota max =====
__global__ __launch_bounds__(256) void k3_out(const float* __restrict__ ws,
                                              float* __restrict__ out) {
    int pt = blockIdx.x, b = blockIdx.y;   // 62 x 2
    int t = threadIdx.x, j = t >> 6, lane = t & 63;
    int p = pt * 4 + j;                    // 0..247 exactly
    int s, o;
    pair_so(p, s, o);
    const float* qp = ws + QPART_OFF + (size_t)b * KS * MM + p;
    float qs = 0.f;
    #pragma unroll
    for (int ks = 0; ks < KS; ++ks) qs += qp[(size_t)ks * MM];
    float inv = 1.0f / qs;
    const float* ess = ws + ES_OFF + (size_t)((b * 2 + 0) * EE + s) * R80;
    const float* eso = ws + ES_OFF + (size_t)((b * 2 + 1) * EE + o) * R80;
    const float* sp = ws + SPART_OFF + ((size_t)(b * KS) * MM + p) * R80;
    float nm = -INFINITY;
    {
        int r = lane;   // 0..63
        float acc = 0.f;
        #pragma unroll
        for (int ks = 0; ks < KS; ++ks) acc += sp[(size_t)ks * MM * R80 + r];
        float v = ess[r] + eso[r] + acc * inv;
        if (r < RR) out[(size_t)(b * PP + p) * (RR + 1) + 1 + r] = v;
        else nm = v;    // r 57..63 are nota rows
    }
    if (lane < 16) {
        int r = 64 + lane;  // 64..79
        float acc = 0.f;
        #pragma unroll
        for (int ks = 0; ks < KS; ++ks) acc += sp[(size_t)ks * MM * R80 + r];
        float v = ess[r] + eso[r] + acc * inv;
        if (r < RR + NN) nm = fmaxf(nm, v);   // 64..76
    }
    #pragma unroll
    for (int off = 32; off > 0; off >>= 1) nm = fmaxf(nm, __shfl_xor(nm, off, 64));
    if (lane == 0) out[(size_t)(b * PP + p) * (RR + 1)] = nm;
}

extern "C" void kernel_launch(void* const* d_in, const int* in_sizes, int n_in,
                              void* d_out, int out_size, void* d_ws, size_t ws_size,
                              hipStream_t stream) {
    const float* seq   = (const float*)d_in[0];
    const float* att   = (const float*)d_in[1];
    const float* rel   = (const float*)d_in[2];
    const float* nota  = (const float*)d_in[3];
    const int*   spans = (const int*)d_in[4];
    float* ws  = (float*)d_ws;
    float* out = (float*)d_out;

    k1_prep<<<NQBLK + NEBLK + NSBLK, 256, 0, stream>>>(seq, att, rel, nota, spans, ws);
    k2_gemm<<<64 + 4, 256, 0, stream>>>(rel, nota, ws);
    k3_out<<<dim3(62, BB), 256, 0, stream>>>(ws, out);
}

// Round 8
// 57.883 us; speedup vs baseline: 1.4725x; 1.4725x over previous
//
#include <hip/hip_runtime.h>
#include <hip/hip_bf16.h>
#include <math.h>

// Problem dims
#define BB 2
#define LL 2048
#define DD 768
#define HH 12
#define EE 32
#define RR 57
#define NN 20
#define PP 248
#define MM 256          // P padded to 256 for MFMA tiles
#define KS 8            // K-split in context GEMM
#define KCH (LL / KS)   // 256

// ws layout (float offsets)
#define ENT_EMB_OFF 0                          // f32 B*E*D
#define A16_OFF   (BB * EE * DD)               // bf16 [B][MM][LL] (unnormalized q)
#define A16_F     (BB * MM * LL / 2)
#define CPART_OFF (A16_OFF + A16_F)            // f32 [KS][B][MM][DD]

#define PT4 4
#define NPT4 62

// kP grid roles
#define NQBLK (BB * 256)          // 512 q blocks (8-l chunks)
#define NEBLK (EE * BB)           // 64 ent_emb blocks

typedef __attribute__((ext_vector_type(8))) short bf16x8;
typedef __attribute__((ext_vector_type(4))) float f32x4;

__device__ __forceinline__ unsigned short f2bf(float f) {
    __hip_bfloat16 h = __float2bfloat16(f);
    return __builtin_bit_cast(unsigned short, h);
}
__device__ __forceinline__ float bf2f(unsigned short u) {
    unsigned int x = ((unsigned int)u) << 16;
    return __builtin_bit_cast(float, x);
}
__device__ __forceinline__ void pair_so(int p, int& s, int& o) {
    s = p / 31;
    int r = p - s * 31;
    o = (r < s) ? r : r + 1;
}

// Kernel P: role Q (att gather -> q rows, 8-l chunks), role E (ent_emb)
__global__ __launch_bounds__(256) void kP(const float* __restrict__ seq,
                                          const float* __restrict__ att,
                                          const int* __restrict__ spans,
                                          float* __restrict__ ws) {
    __shared__ __align__(16) char smem[8 * (EE * HH + 1) * 4 + 128];
    int bid = blockIdx.x;
    int t = threadIdx.x;

    if (bid < NQBLK) {
        // ---- role Q: gather+w-average attention into LDS, 256 pair rows ----
        float (*att_s)[EE * HH + 1] = (float (*)[EE * HH + 1])smem;
        int* sp_s = (int*)(smem + 8 * (EE * HH + 1) * 4);
        int b = bid >> 8, l0 = (bid & 255) * 8;
        if (t < EE) sp_s[t] = spans[b * EE + t];
        __syncthreads();
        // 384 (e,h) rows x 2 segments of 4 l; average the 4 w-rows inline
        for (int i = t; i < EE * HH * 2; i += 256) {
            int seg = i & 1, eh = i >> 1;
            int e = eh / HH, h = eh - e * HH;
            const float* base = att + ((size_t)(b * HH + h) * LL + sp_s[e]) * LL + l0 + seg * 4;
            float4 v0 = *(const float4*)base;
            float4 v1 = *(const float4*)(base + LL);
            float4 v2 = *(const float4*)(base + 2 * LL);
            float4 v3 = *(const float4*)(base + 3 * LL);
            att_s[seg * 4 + 0][eh] = 0.25f * (v0.x + v1.x + v2.x + v3.x);
            att_s[seg * 4 + 1][eh] = 0.25f * (v0.y + v1.y + v2.y + v3.y);
            att_s[seg * 4 + 2][eh] = 0.25f * (v0.z + v1.z + v2.z + v3.z);
            att_s[seg * 4 + 3][eh] = 0.25f * (v0.w + v1.w + v2.w + v3.w);
        }
        __syncthreads();
        int p = t, s, o;
        pair_so(p, s, o);          // pads p>=248 -> s=8, o<=7: valid indices
        float q[8];
        #pragma unroll
        for (int l = 0; l < 8; ++l) {
            float acc = 0.f;
            #pragma unroll
            for (int h = 0; h < HH; ++h) acc += att_s[l][s * HH + h] * att_s[l][o * HH + h];
            q[l] = acc;
        }
        unsigned short* A16 = (unsigned short*)(ws + A16_OFF) + (size_t)(b * MM + p) * LL + l0;
        #pragma unroll
        for (int i = 0; i < 2; ++i) {
            ushort4 ov = make_ushort4(f2bf(q[i * 4 + 0]), f2bf(q[i * 4 + 1]),
                                      f2bf(q[i * 4 + 2]), f2bf(q[i * 4 + 3]));
            *(ushort4*)(A16 + i * 4) = ov;
        }
    } else {
        // ---- role E: ent_emb ----
        int bx = bid - NQBLK;
        int e = bx & 31, b = bx >> 5;
        int st = spans[b * EE + e];
        float* ee = ws + ENT_EMB_OFF + (size_t)(b * EE + e) * DD;
        const float* srow = seq + (size_t)(b * LL + st) * DD;
        for (int d = t; d < DD; d += 256) {
            ee[d] = 0.25f * (srow[d] + srow[DD + d] + srow[2 * DD + d] + srow[3 * DD + d]);
        }
    }
}

// Kernel 3: cpart[ks][b][m][n] = sum_{k in split} A[m][k] * seq[k][n]  (bf16 MFMA)
// B-operand staged directly from f32 seq with fused transpose+cast (no seqT pass).
__global__ __launch_bounds__(256) void k3_gemm(const float* __restrict__ seq,
                                               float* __restrict__ ws) {
    int m0 = blockIdx.x * 64, n0 = blockIdx.y * 64;
    int ks = blockIdx.z & (KS - 1), b = blockIdx.z >> 3;
    const unsigned short* A = (const unsigned short*)(ws + A16_OFF) + (size_t)b * MM * LL;
    __shared__ __align__(16) short As[64][40];
    __shared__ __align__(16) short Bs[64][40];
    int t = threadIdx.x;
    int row = t >> 2, seg = t & 3;          // A staging
    int bl = t >> 3, bd = t & 7;            // B staging: 32 l-rows x 8 d-segs
    int w = t >> 6, lane = t & 63;
    int wr = w >> 1, wc = w & 1;
    int fr = lane & 15, kb = lane >> 4;
    f32x4 acc[2][2] = {};
    int k0c = ks * KCH;
    for (int st = 0; st < KCH / 32; ++st) {
        int kk = k0c + st * 32;
        *(uint4*)&As[row][seg * 8] = *(const uint4*)(A + (size_t)(m0 + row) * LL + kk + seg * 8);
        {
            const float* sp2 = seq + (size_t)(b * LL + kk + bl) * DD + n0 + bd * 8;
            float4 u0 = *(const float4*)sp2;
            float4 u1 = *(const float4*)(sp2 + 4);
            unsigned short bv[8] = {f2bf(u0.x), f2bf(u0.y), f2bf(u0.z), f2bf(u0.w),
                                    f2bf(u1.x), f2bf(u1.y), f2bf(u1.z), f2bf(u1.w)};
            #pragma unroll
            for (int i = 0; i < 8; ++i) Bs[bd * 8 + i][bl] = (short)bv[i];
        }
        __syncthreads();
        bf16x8 af[2], bfr[2];
        #pragma unroll
        for (int i = 0; i < 2; ++i) af[i] = *(bf16x8*)&As[wr * 32 + i * 16 + fr][kb * 8];
        #pragma unroll
        for (int j = 0; j < 2; ++j) bfr[j] = *(bf16x8*)&Bs[wc * 32 + j * 16 + fr][kb * 8];
        #pragma unroll
        for (int i = 0; i < 2; ++i)
            #pragma unroll
            for (int j = 0; j < 2; ++j)
                acc[i][j] = __builtin_amdgcn_mfma_f32_16x16x32_bf16(af[i], bfr[j], acc[i][j], 0, 0, 0);
        __syncthreads();
    }
    float* cp = ws + CPART_OFF + (size_t)((ks * BB + b) * MM) * DD;
    #pragma unroll
    for (int i = 0; i < 2; ++i)
        #pragma unroll
        for (int j = 0; j < 2; ++j)
            #pragma unroll
            for (int r = 0; r < 4; ++r) {
                int gm = m0 + wr * 32 + i * 16 + kb * 4 + r;
                int gn = n0 + wc * 32 + j * 16 + fr;
                cp[(size_t)gm * DD + gn] = acc[i][j][r];
            }
}

// Kernel 4: qsum + register emb + scoring; rows split across 2 block-groups (z)
__global__ __launch_bounds__(256, 1) void k4_score(const float* __restrict__ rel,
                                                   const float* __restrict__ nota,
                                                   const float* __restrict__ ws,
                                                   float* __restrict__ out) {
    int pt = blockIdx.x, b = blockIdx.y, gz = blockIdx.z;
    int tid = threadIdx.x, w = tid >> 6, lane = tid & 63;
    __shared__ float red_s[4][PT4];
    __shared__ float qs_s[PT4];
    __shared__ float nota_s[PT4][NN];
    // phase 0: qsum per pair (from bf16 q rows)
    {
        const unsigned short* A16 =
            (const unsigned short*)(ws + A16_OFF) + (size_t)(b * MM + pt * PT4) * LL;
        #pragma unroll
        for (int j = 0; j < PT4; ++j) {
            ushort4 u0 = *(const ushort4*)(A16 + (size_t)j * LL + tid * 8);
            ushort4 u1 = *(const ushort4*)(A16 + (size_t)j * LL + tid * 8 + 4);
            float v = bf2f(u0.x) + bf2f(u0.y) + bf2f(u0.z) + bf2f(u0.w)
                    + bf2f(u1.x) + bf2f(u1.y) + bf2f(u1.z) + bf2f(u1.w);
            #pragma unroll
            for (int off = 32; off > 0; off >>= 1) v += __shfl_xor(v, off, 64);
            if (lane == 0) red_s[w][j] = v;
        }
        __syncthreads();
        if (tid < PT4)
            qs_s[tid] = 1.0f / (red_s[0][tid] + red_s[1][tid] + red_s[2][tid] + red_s[3][tid]);
        __syncthreads();
    }
    // phase 1: per-lane emb fragments for all 4 pairs
    float4 er[PT4][9];
    #pragma unroll
    for (int j = 0; j < PT4; ++j) {
        int p = pt * PT4 + j;
        int s, o;
        pair_so(p, s, o);
        const float4* es = (const float4*)(ws + ENT_EMB_OFF + (size_t)(b * EE + s) * DD);
        const float4* eo = (const float4*)(ws + ENT_EMB_OFF + (size_t)(b * EE + o) * DD);
        float qs = qs_s[j];
        #pragma unroll
        for (int i4 = 0; i4 < 3; ++i4) er[j][i4] = es[i4 * 64 + lane];
        #pragma unroll
        for (int i4 = 0; i4 < 3; ++i4) er[j][3 + i4] = eo[i4 * 64 + lane];
        #pragma unroll
        for (int i4 = 0; i4 < 3; ++i4) {
            float4 sum = make_float4(0.f, 0.f, 0.f, 0.f);
            #pragma unroll
            for (int ls = 0; ls < KS; ++ls) {
                const float4* cp = (const float4*)(ws + CPART_OFF +
                                   (size_t)((ls * BB + b) * MM + p) * DD);
                float4 v = cp[i4 * 64 + lane];
                sum.x += v.x; sum.y += v.y; sum.z += v.z; sum.w += v.w;
            }
            er[j][6 + i4] = make_float4(sum.x * qs, sum.y * qs, sum.z * qs, sum.w * qs);
        }
    }
    // phase 2: rows [lo,hi) for this group; 2 code rows per iteration
    int lo = (gz == 0) ? 0 : 39;
    int hi = (gz == 0) ? 39 : (RR + NN);
    for (int base = lo + w * 2; base < hi; base += 8) {
        int r1 = base + 1;
        bool has1 = (r1 < hi);
        const float4* code0 = (base < RR)
            ? (const float4*)(rel + (size_t)base * 3 * DD)
            : (const float4*)(nota + (size_t)(base - RR) * 3 * DD);
        const float4* code1 = has1
            ? ((r1 < RR) ? (const float4*)(rel + (size_t)r1 * 3 * DD)
                         : (const float4*)(nota + (size_t)(r1 - RR) * 3 * DD))
            : code0;
        float acc0[PT4] = {0.f, 0.f, 0.f, 0.f};
        float acc1[PT4] = {0.f, 0.f, 0.f, 0.f};
        #pragma unroll
        for (int i4 = 0; i4 < 9; ++i4) {
            float4 c0 = code0[i4 * 64 + lane];
            float4 c1 = code1[i4 * 64 + lane];
            #pragma unroll
            for (int j = 0; j < PT4; ++j) {
                acc0[j] += c0.x * er[j][i4].x + c0.y * er[j][i4].y
                         + c0.z * er[j][i4].z + c0.w * er[j][i4].w;
                acc1[j] += c1.x * er[j][i4].x + c1.y * er[j][i4].y
                         + c1.z * er[j][i4].z + c1.w * er[j][i4].w;
            }
        }
        #pragma unroll
        for (int j = 0; j < PT4; ++j) {
            float v0 = acc0[j], v1 = acc1[j];
            #pragma unroll
            for (int off = 32; off > 0; off >>= 1) {
                v0 += __shfl_xor(v0, off, 64);
                v1 += __shfl_xor(v1, off, 64);
            }
            if (lane == 0) {
                int p = pt * PT4 + j;
                if (base < RR) out[(size_t)(b * PP + p) * (RR + 1) + 1 + base] = v0;
                else nota_s[j][base - RR] = v0;
                if (has1) {
                    if (r1 < RR) out[(size_t)(b * PP + p) * (RR + 1) + 1 + r1] = v1;
                    else nota_s[j][r1 - RR] = v1;
                }
            }
        }
    }
    __syncthreads();
    if (gz == 1 && tid < PT4) {
        float m = -INFINITY;
        #pragma unroll
        for (int n = 0; n < NN; ++n) m = fmaxf(m, nota_s[tid][n]);
        out[(size_t)(b * PP + pt * PT4 + tid) * (RR + 1)] = m;
    }
}

extern "C" void kernel_launch(void* const* d_in, const int* in_sizes, int n_in,
                              void* d_out, int out_size, void* d_ws, size_t ws_size,
                              hipStream_t stream) {
    const float* seq   = (const float*)d_in[0];
    const float* att   = (const float*)d_in[1];
    const float* rel   = (const float*)d_in[2];
    const float* nota  = (const float*)d_in[3];
    const int*   spans = (const int*)d_in[4];
    float* ws  = (float*)d_ws;
    float* out = (float*)d_out;

    kP<<<NQBLK + NEBLK, 256, 0, stream>>>(seq, att, spans, ws);
    k3_gemm<<<dim3(MM / 64, DD / 64, KS * BB), 256, 0, stream>>>(seq, ws);
    k4_score<<<dim3(NPT4, BB, 2), 256, 0, stream>>>(rel, nota, ws, out);
}